// Round 8
// baseline (200.959 us; speedup 1.0000x reference)
//
#include <hip/hip_runtime.h>

// Problem constants (from reference setup_inputs).
#define BATCH  4
#define NQ     8192
#define NA     6890
#define NPAIR  3445   // real anchor pairs per batch
#define NPAD   3456   // padded pairs per batch = 2 tiles x 1728
#define HALF   1728   // pairs per LDS tile (one anchor half)
#define NWAVE  16     // waves per block (1024 threads)
#define PPT    108    // pairs per wave per tile (1728/16)
#define NQG    256    // query groups (128 queries each) across whole problem

typedef float v2f __attribute__((ext_vector_type(2)));

// ---------------------------------------------------------------------------
// Split-anchor fused kernel: QPT=2 (halves LDS reads/CU -> 23 us floor) AND
// 512 blocks (2/CU, 8 waves/SIMD -> stall covered, proven in R7).
//
// Block (qg, half): stages anchor-pair tile `half` (1728 pairs, 55.3 KB,
// packed inline to (x0,x1,y0,y1)(z0,z1,h0,h1), h = 0.5*|a|^2, pads h=1e30),
// scans it against its 128 queries (thread -> lane, lane+64), block-reduces
// to 128 partial argmin keys. Cross-half combine without grid sync:
//   partial -> plain store pkeys[half][gid]; __threadfence();
//   one atomicAdd on counter[qg]; the block seeing old==1 (arrives last,
//   never waits) atomic-reads the partner's keys, mins, and finalizes
//   (exact d2/dot recompute, ballot, one atomicAdd per wave).
// Keys: score = h + hq - q.a = 0.5*||q-a||^2 >= 0 -> float bits order as
// uint; key = (bits & 0xFFFFE000) | anchor_idx. Global min over keys is
// partition-independent -> same winner as rounds 5-7 (absmax 0).
// ---------------------------------------------------------------------------
__global__ __launch_bounds__(NWAVE * 64, 8)
void collision_split_kernel(const float* __restrict__ query,
                            const float* __restrict__ anchor,
                            const float* __restrict__ normals,
                            unsigned* __restrict__ pkeys,     // [2][BATCH*NQ]
                            unsigned* __restrict__ counters,  // [NQG]
                            float* __restrict__ out) {
    __shared__ union {
        float4   st[HALF * 2];        // 1728 pairs x 32 B = 55296 B
        unsigned key[NWAVE][128];     // 8 KB overlay for the block reduction
    } sh;
    __shared__ int s_fin;

    const int tid  = threadIdx.x;
    const int lane = tid & 63;
    const int wave = __builtin_amdgcn_readfirstlane(tid >> 6);
    const int qg   = blockIdx.x >> 1;          // query group (128 queries)
    const int half = blockIdx.x & 1;           // which anchor half
    const int b    = qg >> 6;                  // 64 groups per batch
    const int qbase = (qg & 63) * 128;

    // Per-thread queries: lane and lane+64 of the group's 128.
    const float* qp0 = query + ((size_t)b * NQ + qbase + lane) * 3;
    const float* qp1 = qp0 + 64 * 3;
    const float q0x = qp0[0], q0y = qp0[1], q0z = qp0[2];
    const float q1x = qp1[0], q1y = qp1[1], q1z = qp1[2];
    const float hq0 = 0.5f * (q0x*q0x + q0y*q0y + q0z*q0z);
    const float hq1 = 0.5f * (q1x*q1x + q1y*q1y + q1z*q1z);
    const v2f nq0x = {-q0x,-q0x}, nq0y = {-q0y,-q0y}, nq0z = {-q0z,-q0z};
    const v2f nq1x = {-q1x,-q1x}, nq1y = {-q1y,-q1y}, nq1z = {-q1z,-q1z};
    const v2f hq0v = {hq0,hq0}, hq1v = {hq1,hq1};

    const float* __restrict__ Araw = anchor + (size_t)b * NA * 3;

    // ---- stage this block's tile: pairs [half*HALF, half*HALF+HALF) ----
    for (int p = tid; p < HALF; p += NWAVE * 64) {
        const int gp = half * HALF + p;       // pair index in [0, NPAD)
        float4 A, B;
        if (gp < NPAIR) {                     // NA even -> pair fully real
            const float* s = Araw + (size_t)6 * gp;
            const float x0 = s[0], y0 = s[1], z0 = s[2];
            const float x1 = s[3], y1 = s[4], z1 = s[5];
            A = make_float4(x0, x1, y0, y1);
            B = make_float4(z0, z1,
                            0.5f * (x0*x0 + y0*y0 + z0*z0),
                            0.5f * (x1*x1 + y1*y1 + z1*z1));
        } else {                              // sentinel pad: never wins
            A = make_float4(0.f, 0.f, 0.f, 0.f);
            B = make_float4(0.f, 0.f, 1e30f, 1e30f);
        }
        sh.st[2*p]   = A;
        sh.st[2*p+1] = B;
    }
    __syncthreads();

    // ---- compute: this wave's private 108-pair slab, both queries ----
    const int base = wave * PPT;
    const int k0   = 2 * (half * HALF + base);        // global anchor index
    const float4* S = sh.st + (size_t)2 * base;

    unsigned best00 = 0xFFFFFFFFu, best01 = 0xFFFFFFFFu;   // query 0
    unsigned best10 = 0xFFFFFFFFu, best11 = 0xFFFFFFFFu;   // query 1

    #pragma unroll 4
    for (int p = 0; p < PPT; ++p) {
        const float4 A  = S[2*p];      // x0,x1,y0,y1  (broadcast ds_read)
        const float4 Bq = S[2*p+1];    // z0,z1,h0,h1
        const v2f X = {A.x,  A.y},  Y = {A.z,  A.w};
        const v2f Z = {Bq.x, Bq.y}, H = {Bq.z, Bq.w};
        const unsigned idx = (unsigned)(k0 + 2*p);
        const v2f h0 = H + hq0v;
        const v2f s0 = __builtin_elementwise_fma(X, nq0x,
                         __builtin_elementwise_fma(Y, nq0y,
                           __builtin_elementwise_fma(Z, nq0z, h0)));
        const v2f h1 = H + hq1v;
        const v2f s1 = __builtin_elementwise_fma(X, nq1x,
                         __builtin_elementwise_fma(Y, nq1y,
                           __builtin_elementwise_fma(Z, nq1z, h1)));
        unsigned k;
        k = (__float_as_uint(s0.x) & 0xFFFFE000u) |  idx;      best00 = k < best00 ? k : best00;
        k = (__float_as_uint(s0.y) & 0xFFFFE000u) | (idx + 1); best01 = k < best01 ? k : best01;
        k = (__float_as_uint(s1.x) & 0xFFFFE000u) |  idx;      best10 = k < best10 ? k : best10;
        k = (__float_as_uint(s1.y) & 0xFFFFE000u) | (idx + 1); best11 = k < best11 ? k : best11;
    }

    __syncthreads();   // slab reads done before overlay write
    sh.key[wave][lane]      = best01 < best00 ? best01 : best00;
    sh.key[wave][64 + lane] = best11 < best10 ? best11 : best10;
    __syncthreads();

    // ---- block reduction + publish partial ----
    unsigned bk = 0xFFFFFFFFu;
    const size_t gid = (size_t)b * NQ + qbase + tid;   // valid when tid<128
    if (tid < 128) {
        bk = sh.key[0][tid];
        #pragma unroll
        for (int w = 1; w < NWAVE; ++w) {
            const unsigned v = sh.key[w][tid];
            bk = v < bk ? v : bk;
        }
        pkeys[(size_t)half * (BATCH * NQ) + gid] = bk;   // plain store
    }
    __threadfence();       // make stores visible at device scope
    __syncthreads();       // all lanes fenced before the counter bump

    if (tid == 0) {
        const unsigned old = atomicAdd(&counters[qg], 1u);
        s_fin = (old == 1);   // later of the two blocks finalizes (no wait)
    }
    __syncthreads();

    if (s_fin && tid < 128) {
        // Partner's partial via device-scope atomic read (coherent cross-XCD).
        const unsigned other =
            atomicMin(&pkeys[(size_t)(half ^ 1) * (BATCH * NQ) + gid], 0xFFFFFFFFu);
        const unsigned fk = other < bk ? other : bk;
        const int bidx = (int)(fk & 8191u);
        // Thread tid finalizes query qbase+tid (wave0 -> its q0, wave1 -> q1).
        const bool hi = tid >= 64;
        const float qx = hi ? q1x : q0x;
        const float qy = hi ? q1y : q0y;
        const float qz = hi ? q1z : q0z;
        const float* ap   = Araw + (size_t)bidx * 3;
        const float* npnt = normals + ((size_t)b * NA + bidx) * 3;
        const float dx = qx - ap[0], dy = qy - ap[1], dz = qz - ap[2];
        const float d2  = fmaf(dz, dz, fmaf(dy, dy, dx * dx));
        const float dot = fmaf(dz, npnt[2], fmaf(dy, npnt[1], dx * npnt[0]));
        // dot * (l2 <= 0.5) < 0  <=>  dot < 0 && d2 <= 0.25
        const bool coll = (dot < 0.0f) && (d2 <= 0.25f);
        const unsigned long long m = __ballot(coll);
        if (lane == 0) atomicAdd(out + b, (float)__popcll(m));
    }
}

// ---------------------------------------------------------------------------
// Fallback (round-7 kernel, verbatim) if workspace is too small.
// ---------------------------------------------------------------------------
__global__ __launch_bounds__(NWAVE * 64, 8)
void collision_occ_kernel(const float* __restrict__ query,
                          const float* __restrict__ anchor,
                          const float* __restrict__ normals,
                          float* __restrict__ out) {
    __shared__ union {
        float4   st[HALF * 2];
        unsigned key[NWAVE][64];
    } sh;

    const int tid  = threadIdx.x;
    const int lane = tid & 63;
    const int wave = __builtin_amdgcn_readfirstlane(tid >> 6);
    const int b = blockIdx.x >> 7;
    const int q = (blockIdx.x & 127) * 64 + lane;

    const float* qp = query + ((size_t)b * NQ + q) * 3;
    const float qx = qp[0], qy = qp[1], qz = qp[2];
    const float hq = 0.5f * (qx*qx + qy*qy + qz*qz);
    const v2f nqx = {-qx,-qx}, nqy = {-qy,-qy}, nqz = {-qz,-qz};
    const v2f hqv = {hq, hq};

    const float* __restrict__ Araw = anchor + (size_t)b * NA * 3;

    unsigned best0 = 0xFFFFFFFFu, best1 = 0xFFFFFFFFu;

    #pragma unroll 1
    for (int t = 0; t < 2; ++t) {
        for (int p = tid; p < HALF; p += NWAVE * 64) {
            const int gp = t * HALF + p;
            float4 A, B;
            if (gp < NPAIR) {
                const float* s = Araw + (size_t)6 * gp;
                const float x0 = s[0], y0 = s[1], z0 = s[2];
                const float x1 = s[3], y1 = s[4], z1 = s[5];
                A = make_float4(x0, x1, y0, y1);
                B = make_float4(z0, z1,
                                0.5f * (x0*x0 + y0*y0 + z0*z0),
                                0.5f * (x1*x1 + y1*y1 + z1*z1));
            } else {
                A = make_float4(0.f, 0.f, 0.f, 0.f);
                B = make_float4(0.f, 0.f, 1e30f, 1e30f);
            }
            sh.st[2*p]   = A;
            sh.st[2*p+1] = B;
        }
        __syncthreads();

        const int base = wave * PPT;
        const int k0   = 2 * (t * HALF + base);
        const float4* S = sh.st + (size_t)2 * base;

        #pragma unroll 4
        for (int p = 0; p < PPT; ++p) {
            const float4 A  = S[2*p];
            const float4 Bq = S[2*p+1];
            const v2f X = {A.x,  A.y},  Y = {A.z,  A.w};
            const v2f Z = {Bq.x, Bq.y}, H = {Bq.z, Bq.w};
            const unsigned idx = (unsigned)(k0 + 2*p);
            const v2f h = H + hqv;
            const v2f s = __builtin_elementwise_fma(X, nqx,
                            __builtin_elementwise_fma(Y, nqy,
                              __builtin_elementwise_fma(Z, nqz, h)));
            unsigned k;
            k = (__float_as_uint(s.x) & 0xFFFFE000u) |  idx;      best0 = k < best0 ? k : best0;
            k = (__float_as_uint(s.y) & 0xFFFFE000u) | (idx + 1); best1 = k < best1 ? k : best1;
        }
        __syncthreads();
    }

    sh.key[wave][lane] = best1 < best0 ? best1 : best0;
    __syncthreads();

    if (tid < 64) {
        unsigned bk = sh.key[0][lane];
        #pragma unroll
        for (int w = 1; w < NWAVE; ++w) {
            const unsigned v = sh.key[w][lane];
            bk = v < bk ? v : bk;
        }
        const int bidx = (int)(bk & 8191u);
        const float* ap   = Araw + (size_t)bidx * 3;
        const float* npnt = normals + ((size_t)b * NA + bidx) * 3;
        const float dx = qx - ap[0], dy = qy - ap[1], dz = qz - ap[2];
        const float d2  = fmaf(dz, dz, fmaf(dy, dy, dx * dx));
        const float dot = fmaf(dz, npnt[2], fmaf(dy, npnt[1], dx * npnt[0]));
        const bool coll = (dot < 0.0f) && (d2 <= 0.25f);
        const unsigned long long m = __ballot(coll);
        if (lane == 0) atomicAdd(out + b, (float)__popcll(m));
    }
}

extern "C" void kernel_launch(void* const* d_in, const int* in_sizes, int n_in,
                              void* d_out, int out_size, void* d_ws, size_t ws_size,
                              hipStream_t stream) {
    const float* query   = (const float*)d_in[0];
    const float* anchor  = (const float*)d_in[1];
    const float* normals = (const float*)d_in[2];
    float* out = (float*)d_out;

    // d_out is poisoned with 0xAA before every call — zero it (graph-safe).
    hipMemsetAsync(d_out, 0, (size_t)out_size * sizeof(float), stream);

    const size_t CNT_BYTES  = (size_t)NQG * sizeof(unsigned);            // 1 KB
    const size_t PKEY_BYTES = (size_t)2 * BATCH * NQ * sizeof(unsigned); // 256 KB
    const size_t WS_NEED    = CNT_BYTES + PKEY_BYTES;

    if (d_ws && ws_size >= WS_NEED) {
        unsigned* counters = (unsigned*)d_ws;
        unsigned* pkeys    = (unsigned*)((char*)d_ws + CNT_BYTES);
        // Counters must start at 0 each call (ws is poisoned). pkeys need no
        // init: both halves are stored before either is read.
        hipMemsetAsync(counters, 0, CNT_BYTES, stream);
        // 512 blocks x 1024 threads: 256 query groups x 2 anchor halves
        // (2 blocks/CU, 110.6 KB LDS/CU, 32 waves/CU = 8 waves/SIMD).
        collision_split_kernel<<<dim3(NQG * 2), dim3(NWAVE * 64), 0, stream>>>(
            query, anchor, normals, pkeys, counters, out);
    } else {
        collision_occ_kernel<<<dim3(BATCH * (NQ / 64)), dim3(NWAVE * 64), 0, stream>>>(
            query, anchor, normals, out);
    }
}

// Round 9
// 94.623 us; speedup vs baseline: 2.1238x; 2.1238x over previous
//
#include <hip/hip_runtime.h>

// Problem constants (from reference setup_inputs).
#define BATCH  4
#define NQ     8192
#define NA     6890
#define NPAIR  3445   // real anchor pairs per batch
#define NPAD   3456   // padded pairs per batch = 2 tiles x 1728
#define HALF   1728   // pairs per LDS tile (one anchor half)
#define NWAVE  16     // waves per block (1024 threads)
#define PPT    108    // pairs per wave per tile (1728/16)
#define NQG    256    // query groups (128 queries each)

typedef float v2f __attribute__((ext_vector_type(2)));

// ---------------------------------------------------------------------------
// Dispatch 1: split-anchor main kernel. QPT=2 (6912 ds_read_b128/CU -> 23 us
// LDS floor) AND 512 blocks (2/CU, 8 waves/SIMD -> latency covered, R7).
// Block (qg, half): stages anchor-pair tile `half` (1728 pairs, 55.3 KB,
// packed inline to (x0,x1,y0,y1)(z0,z1,h0,h1), h = 0.5*|a|^2, pads h=1e30),
// scans against its 128 queries (thread -> lane, lane+64), block-reduces to
// 128 partial argmin keys, PLAIN-stores them to pkeys[half][gid].
// NO fences, NO device atomics (R8 post-mortem: in-kernel device-scope
// fence/atomic combine convoyed the grid, +120 us). Cross-half visibility
// comes from the kernel boundary (runtime flushes L2 between dispatches).
// Keys: score = h + hq - q.a = 0.5*||q-a||^2 >= 0 -> float bits order as
// uint; key = (bits & 0xFFFFE000) | idx; global min == first-occurrence
// argmin (idx in low bits). Same quantization as rounds 4-8 (absmax 0).
// ---------------------------------------------------------------------------
__global__ __launch_bounds__(NWAVE * 64, 8)
void collision_split2_kernel(const float* __restrict__ query,
                             const float* __restrict__ anchor,
                             unsigned* __restrict__ pkeys) {   // [2][BATCH*NQ]
    __shared__ union {
        float4   st[HALF * 2];        // 1728 pairs x 32 B = 55296 B
        unsigned key[NWAVE][128];     // 8 KB overlay for the block reduction
    } sh;

    const int tid  = threadIdx.x;
    const int lane = tid & 63;
    const int wave = __builtin_amdgcn_readfirstlane(tid >> 6);
    const int qg   = blockIdx.x >> 1;          // query group (128 queries)
    const int half = blockIdx.x & 1;           // which anchor half
    const int b    = qg >> 6;                  // 64 groups per batch
    const int qbase = (qg & 63) * 128;

    // Per-thread queries: lane and lane+64 of the group's 128.
    const float* qp0 = query + ((size_t)b * NQ + qbase + lane) * 3;
    const float* qp1 = qp0 + 64 * 3;
    const float q0x = qp0[0], q0y = qp0[1], q0z = qp0[2];
    const float q1x = qp1[0], q1y = qp1[1], q1z = qp1[2];
    const float hq0 = 0.5f * (q0x*q0x + q0y*q0y + q0z*q0z);
    const float hq1 = 0.5f * (q1x*q1x + q1y*q1y + q1z*q1z);
    const v2f nq0x = {-q0x,-q0x}, nq0y = {-q0y,-q0y}, nq0z = {-q0z,-q0z};
    const v2f nq1x = {-q1x,-q1x}, nq1y = {-q1y,-q1y}, nq1z = {-q1z,-q1z};
    const v2f hq0v = {hq0,hq0}, hq1v = {hq1,hq1};

    const float* __restrict__ Araw = anchor + (size_t)b * NA * 3;

    // ---- stage this block's tile: pairs [half*HALF, half*HALF+HALF) ----
    for (int p = tid; p < HALF; p += NWAVE * 64) {
        const int gp = half * HALF + p;       // pair index in [0, NPAD)
        float4 A, B;
        if (gp < NPAIR) {                     // NA even -> pair fully real
            const float* s = Araw + (size_t)6 * gp;
            const float x0 = s[0], y0 = s[1], z0 = s[2];
            const float x1 = s[3], y1 = s[4], z1 = s[5];
            A = make_float4(x0, x1, y0, y1);
            B = make_float4(z0, z1,
                            0.5f * (x0*x0 + y0*y0 + z0*z0),
                            0.5f * (x1*x1 + y1*y1 + z1*z1));
        } else {                              // sentinel pad: never wins
            A = make_float4(0.f, 0.f, 0.f, 0.f);
            B = make_float4(0.f, 0.f, 1e30f, 1e30f);
        }
        sh.st[2*p]   = A;
        sh.st[2*p+1] = B;
    }
    __syncthreads();

    // ---- compute: this wave's private 108-pair slab, both queries ----
    const int base = wave * PPT;
    const int k0   = 2 * (half * HALF + base);        // global anchor index
    const float4* S = sh.st + (size_t)2 * base;

    unsigned best0 = 0xFFFFFFFFu;   // query 0
    unsigned best1 = 0xFFFFFFFFu;   // query 1

    #pragma unroll 4
    for (int p = 0; p < PPT; ++p) {
        const float4 A  = S[2*p];      // x0,x1,y0,y1  (broadcast ds_read)
        const float4 Bq = S[2*p+1];    // z0,z1,h0,h1
        const v2f X = {A.x,  A.y},  Y = {A.z,  A.w};
        const v2f Z = {Bq.x, Bq.y}, H = {Bq.z, Bq.w};
        const unsigned idx = (unsigned)(k0 + 2*p);
        const v2f h0 = H + hq0v;
        const v2f s0 = __builtin_elementwise_fma(X, nq0x,
                         __builtin_elementwise_fma(Y, nq0y,
                           __builtin_elementwise_fma(Z, nq0z, h0)));
        const v2f h1 = H + hq1v;
        const v2f s1 = __builtin_elementwise_fma(X, nq1x,
                         __builtin_elementwise_fma(Y, nq1y,
                           __builtin_elementwise_fma(Z, nq1z, h1)));
        // (bits & mask) | idx -> v_and_or_b32; min(min(a,b),c) -> v_min3_u32
        const unsigned kA0 = (__float_as_uint(s0.x) & 0xFFFFE000u) |  idx;
        const unsigned kB0 = (__float_as_uint(s0.y) & 0xFFFFE000u) | (idx + 1);
        const unsigned m0  = kA0 < kB0 ? kA0 : kB0;
        best0 = m0 < best0 ? m0 : best0;
        const unsigned kA1 = (__float_as_uint(s1.x) & 0xFFFFE000u) |  idx;
        const unsigned kB1 = (__float_as_uint(s1.y) & 0xFFFFE000u) | (idx + 1);
        const unsigned m1  = kA1 < kB1 ? kA1 : kB1;
        best1 = m1 < best1 ? m1 : best1;
    }

    __syncthreads();   // slab reads done before overlay write
    sh.key[wave][lane]      = best0;
    sh.key[wave][64 + lane] = best1;
    __syncthreads();

    // ---- block reduction + publish partial (plain store) ----
    if (tid < 128) {
        unsigned bk = sh.key[0][tid];
        #pragma unroll
        for (int w = 1; w < NWAVE; ++w) {
            const unsigned v = sh.key[w][tid];
            bk = v < bk ? v : bk;
        }
        pkeys[(size_t)half * (BATCH * NQ) + (size_t)b * NQ + qbase + tid] = bk;
    }
}

// ---------------------------------------------------------------------------
// Dispatch 2: finalize. Min the two halves per query, exact d2/dot recompute
// for the winner (identical math to rounds 0-8), ballot + 1 atomic per wave.
// Kernel boundary guarantees visibility of dispatch-1 plain stores.
// ---------------------------------------------------------------------------
__global__ void finalize_kernel(const float* __restrict__ query,
                                const float* __restrict__ anchor,
                                const float* __restrict__ normals,
                                const unsigned* __restrict__ pkeys,
                                float* __restrict__ out) {
    const int tid = blockIdx.x * 256 + (int)threadIdx.x;
    const int b  = tid >> 13;           // 8192 queries per batch
    const int qi = tid & 8191;
    const unsigned kh0 = pkeys[tid];
    const unsigned kh1 = pkeys[(size_t)BATCH * NQ + tid];
    const unsigned bk  = kh1 < kh0 ? kh1 : kh0;
    const int bidx = (int)(bk & 8191u);
    const float* qp  = query   + ((size_t)b * NQ + qi)   * 3;
    const float* ap  = anchor  + ((size_t)b * NA + bidx) * 3;
    const float* np2 = normals + ((size_t)b * NA + bidx) * 3;
    const float qx = qp[0], qy = qp[1], qz = qp[2];
    const float dx = qx - ap[0], dy = qy - ap[1], dz = qz - ap[2];
    const float d2  = fmaf(dz, dz, fmaf(dy, dy, dx * dx));
    const float dot = fmaf(dz, np2[2], fmaf(dy, np2[1], dx * np2[0]));
    // dot * (l2 <= 0.5) < 0  <=>  dot < 0 && d2 <= 0.25
    const bool coll = (dot < 0.0f) && (d2 <= 0.25f);
    const unsigned long long m = __ballot(coll);
    if ((threadIdx.x & 63) == 0) atomicAdd(out + b, (float)__popcll(m));
}

// ---------------------------------------------------------------------------
// Fallback (round-7 kernel, verbatim) if workspace is too small.
// ---------------------------------------------------------------------------
__global__ __launch_bounds__(NWAVE * 64, 8)
void collision_occ_kernel(const float* __restrict__ query,
                          const float* __restrict__ anchor,
                          const float* __restrict__ normals,
                          float* __restrict__ out) {
    __shared__ union {
        float4   st[HALF * 2];
        unsigned key[NWAVE][64];
    } sh;

    const int tid  = threadIdx.x;
    const int lane = tid & 63;
    const int wave = __builtin_amdgcn_readfirstlane(tid >> 6);
    const int b = blockIdx.x >> 7;
    const int q = (blockIdx.x & 127) * 64 + lane;

    const float* qp = query + ((size_t)b * NQ + q) * 3;
    const float qx = qp[0], qy = qp[1], qz = qp[2];
    const float hq = 0.5f * (qx*qx + qy*qy + qz*qz);
    const v2f nqx = {-qx,-qx}, nqy = {-qy,-qy}, nqz = {-qz,-qz};
    const v2f hqv = {hq, hq};

    const float* __restrict__ Araw = anchor + (size_t)b * NA * 3;

    unsigned best0 = 0xFFFFFFFFu, best1 = 0xFFFFFFFFu;

    #pragma unroll 1
    for (int t = 0; t < 2; ++t) {
        for (int p = tid; p < HALF; p += NWAVE * 64) {
            const int gp = t * HALF + p;
            float4 A, B;
            if (gp < NPAIR) {
                const float* s = Araw + (size_t)6 * gp;
                const float x0 = s[0], y0 = s[1], z0 = s[2];
                const float x1 = s[3], y1 = s[4], z1 = s[5];
                A = make_float4(x0, x1, y0, y1);
                B = make_float4(z0, z1,
                                0.5f * (x0*x0 + y0*y0 + z0*z0),
                                0.5f * (x1*x1 + y1*y1 + z1*z1));
            } else {
                A = make_float4(0.f, 0.f, 0.f, 0.f);
                B = make_float4(0.f, 0.f, 1e30f, 1e30f);
            }
            sh.st[2*p]   = A;
            sh.st[2*p+1] = B;
        }
        __syncthreads();

        const int base = wave * PPT;
        const int k0   = 2 * (t * HALF + base);
        const float4* S = sh.st + (size_t)2 * base;

        #pragma unroll 4
        for (int p = 0; p < PPT; ++p) {
            const float4 A  = S[2*p];
            const float4 Bq = S[2*p+1];
            const v2f X = {A.x,  A.y},  Y = {A.z,  A.w};
            const v2f Z = {Bq.x, Bq.y}, H = {Bq.z, Bq.w};
            const unsigned idx = (unsigned)(k0 + 2*p);
            const v2f h = H + hqv;
            const v2f s = __builtin_elementwise_fma(X, nqx,
                            __builtin_elementwise_fma(Y, nqy,
                              __builtin_elementwise_fma(Z, nqz, h)));
            unsigned k;
            k = (__float_as_uint(s.x) & 0xFFFFE000u) |  idx;      best0 = k < best0 ? k : best0;
            k = (__float_as_uint(s.y) & 0xFFFFE000u) | (idx + 1); best1 = k < best1 ? k : best1;
        }
        __syncthreads();
    }

    sh.key[wave][lane] = best1 < best0 ? best1 : best0;
    __syncthreads();

    if (tid < 64) {
        unsigned bk = sh.key[0][lane];
        #pragma unroll
        for (int w = 1; w < NWAVE; ++w) {
            const unsigned v = sh.key[w][lane];
            bk = v < bk ? v : bk;
        }
        const int bidx = (int)(bk & 8191u);
        const float* ap   = Araw + (size_t)bidx * 3;
        const float* npnt = normals + ((size_t)b * NA + bidx) * 3;
        const float dx = qx - ap[0], dy = qy - ap[1], dz = qz - ap[2];
        const float d2  = fmaf(dz, dz, fmaf(dy, dy, dx * dx));
        const float dot = fmaf(dz, npnt[2], fmaf(dy, npnt[1], dx * npnt[0]));
        const bool coll = (dot < 0.0f) && (d2 <= 0.25f);
        const unsigned long long m = __ballot(coll);
        if (lane == 0) atomicAdd(out + b, (float)__popcll(m));
    }
}

extern "C" void kernel_launch(void* const* d_in, const int* in_sizes, int n_in,
                              void* d_out, int out_size, void* d_ws, size_t ws_size,
                              hipStream_t stream) {
    const float* query   = (const float*)d_in[0];
    const float* anchor  = (const float*)d_in[1];
    const float* normals = (const float*)d_in[2];
    float* out = (float*)d_out;

    // d_out is poisoned with 0xAA before every call — zero it (graph-safe).
    hipMemsetAsync(d_out, 0, (size_t)out_size * sizeof(float), stream);

    const size_t PKEY_BYTES = (size_t)2 * BATCH * NQ * sizeof(unsigned); // 256 KB

    if (d_ws && ws_size >= PKEY_BYTES) {
        unsigned* pkeys = (unsigned*)d_ws;
        // No pkeys init needed: every slot is written in dispatch 1 before
        // being read in dispatch 2 (kernel boundary orders + flushes).
        // 512 blocks x 1024 threads: 256 query groups x 2 anchor halves
        // (2 blocks/CU, 110.6 KB LDS/CU, 32 waves/CU = 8 waves/SIMD).
        collision_split2_kernel<<<dim3(NQG * 2), dim3(NWAVE * 64), 0, stream>>>(
            query, anchor, pkeys);
        finalize_kernel<<<dim3(BATCH * NQ / 256), dim3(256), 0, stream>>>(
            query, anchor, normals, pkeys, out);
    } else {
        collision_occ_kernel<<<dim3(BATCH * (NQ / 64)), dim3(NWAVE * 64), 0, stream>>>(
            query, anchor, normals, out);
    }
}